// Round 3
// baseline (2742.517 us; speedup 1.0000x reference)
//
#include <hip/hip_runtime.h>
#include <hip/hip_bf16.h>

#define DEV_INLINE __device__ __forceinline__

DEV_INLINE float gelu_exact(float x) {
    return 0.5f * x * (1.0f + erff(x * 0.70710678118654752440f));
}
DEV_INLINE double gelu64(double x) {
    return 0.5 * x * (1.0 + erf(x * 0.70710678118654752440));
}

// ---------------- conv1 (f64): ts (16,100,2048) f32 -> relu(causal conv d=1) -> h1 (16,64,2048) f64
__global__ __launch_bounds__(256) void conv1_kernel64(
    const float* __restrict__ x, const float* __restrict__ w,
    const float* __restrict__ bias, double* __restrict__ y)
{
    const int b = blockIdx.y;
    const int t0 = blockIdx.x * 32;
    __shared__ double xs[100][34];
    for (int e = threadIdx.x; e < 100 * 34; e += 256) {
        int i = e / 34, u = e - i * 34;
        int t = t0 - 2 + u;
        xs[i][u] = (t >= 0) ? (double)x[(b * 100 + i) * 2048 + t] : 0.0;
    }
    __syncthreads();
    const int o = threadIdx.x & 63;
    const int ts = (threadIdx.x >> 6) * 8;
    double acc[8];
    double bv = (double)bias[o];
#pragma unroll
    for (int j = 0; j < 8; ++j) acc[j] = bv;
    const float* wo = w + o * 300;
    for (int i = 0; i < 100; ++i) {
        double w0 = (double)wo[i * 3 + 0], w1 = (double)wo[i * 3 + 1], w2 = (double)wo[i * 3 + 2];
#pragma unroll
        for (int j = 0; j < 8; ++j) {
            acc[j] = fma(w0, xs[i][ts + j],
                     fma(w1, xs[i][ts + j + 1],
                     fma(w2, xs[i][ts + j + 2], acc[j])));
        }
    }
#pragma unroll
    for (int j = 0; j < 8; ++j)
        y[(b * 64 + o) * 2048 + t0 + ts + j] = fmax(acc[j], 0.0);
}

// ---------------- conv2 (f64): h1 -> relu(causal conv d=2) -> xt64 (16,2048,128) transposed
__global__ __launch_bounds__(256) void conv2_kernel64(
    const double* __restrict__ x, const float* __restrict__ w,
    const float* __restrict__ bias, double* __restrict__ xt)
{
    const int b = blockIdx.y;
    const int t0 = blockIdx.x * 32;
    __shared__ double xs[64][36];
    for (int e = threadIdx.x; e < 64 * 36; e += 256) {
        int i = e / 36, u = e - i * 36;
        int t = t0 - 4 + u;
        xs[i][u] = (t >= 0) ? x[(b * 64 + i) * 2048 + t] : 0.0;
    }
    __syncthreads();
    const int o = threadIdx.x & 127;
    const int ts = (threadIdx.x >> 7) * 16;
    double acc[16];
    double bv = (double)bias[o];
#pragma unroll
    for (int j = 0; j < 16; ++j) acc[j] = bv;
    const float* wo = w + o * 192;
    for (int i = 0; i < 64; ++i) {
        double w0 = (double)wo[i * 3 + 0], w1 = (double)wo[i * 3 + 1], w2 = (double)wo[i * 3 + 2];
#pragma unroll
        for (int j = 0; j < 16; ++j) {
            acc[j] = fma(w0, xs[i][ts + j],
                     fma(w1, xs[i][ts + j + 2],
                     fma(w2, xs[i][ts + j + 4], acc[j])));
        }
    }
#pragma unroll
    for (int j = 0; j < 16; ++j)
        xt[(size_t)(b * 2048 + t0 + ts + j) * 128 + o] = fmax(acc[j], 0.0);
}

// ---------------- norm32: from xt64, emit xn32 (normalized, f32) and sq32 for stage-1 ranking
__global__ __launch_bounds__(256) void norm32_kernel(
    const double* __restrict__ xt64, float* __restrict__ xn, float* __restrict__ sq)
{
    const int row = blockIdx.x * 4 + (threadIdx.x >> 6);
    const int lane = threadIdx.x & 63;
    double v0 = xt64[(size_t)row * 128 + lane * 2];
    double v1 = xt64[(size_t)row * 128 + lane * 2 + 1];
    double s = v0 * v0 + v1 * v1;
#pragma unroll
    for (int off = 32; off > 0; off >>= 1) s += __shfl_xor(s, off);
    double inv = 1.0 / fmax(sqrt(s), 1e-12);
    double x0 = v0 * inv, x1 = v1 * inv;
    xn[(size_t)row * 128 + lane * 2]     = (float)x0;
    xn[(size_t)row * 128 + lane * 2 + 1] = (float)x1;
    double q = x0 * x0 + x1 * x1;
#pragma unroll
    for (int off = 32; off > 0; off >>= 1) q += __shfl_xor(q, off);
    if (lane == 0) sq[row] = (float)q;
}

// ---------------- knn stage 1 (f32): per (b,n) top-12 CANDIDATES by 2*dot - sq_m
__global__ __launch_bounds__(256) void knn_kernel(
    const float* __restrict__ xn, const float* __restrict__ sq, int* __restrict__ cand_out)
{
    const int b = blockIdx.y;
    const int n0 = blockIdx.x * 64;
    const float* Xb = xn + (size_t)b * 2048 * 128;
    const float* sqb = sq + b * 2048;

    __shared__ float smem[64 * 132 + 128 * 132 + 128];
    float (*Ra)[132] = (float (*)[132])smem;
    float (*Ma)[132] = (float (*)[132])(smem + 64 * 132);
    float* sqm = smem + 64 * 132 + 128 * 132;

    for (int e = threadIdx.x; e < 64 * 32; e += 256) {
        int r = e >> 5, q = e & 31;
        *(float4*)&Ra[r][q * 4] = *(const float4*)(Xb + (size_t)(n0 + r) * 128 + q * 4);
    }

    const int ri = threadIdx.x >> 4;
    const int ci = threadIdx.x & 15;

    float tv[4][9];
    int   ti[4][9];
#pragma unroll
    for (int q = 0; q < 4; ++q)
#pragma unroll
        for (int t = 0; t < 9; ++t) { tv[q][t] = -3.0e38f; ti[q][t] = -1; }

    for (int m0 = 0; m0 < 2048; m0 += 128) {
        __syncthreads();
        for (int e = threadIdx.x; e < 128 * 32; e += 256) {
            int r = e >> 5, q = e & 31;
            *(float4*)&Ma[r][q * 4] = *(const float4*)(Xb + (size_t)(m0 + r) * 128 + q * 4);
        }
        if (threadIdx.x < 128) sqm[threadIdx.x] = sqb[m0 + threadIdx.x];
        __syncthreads();

        float acc[4][8];
#pragma unroll
        for (int q = 0; q < 4; ++q)
#pragma unroll
            for (int v = 0; v < 8; ++v) acc[q][v] = 0.0f;

        for (int c = 0; c < 128; c += 4) {
            float4 a4[4];
#pragma unroll
            for (int q = 0; q < 4; ++q) a4[q] = *(const float4*)&Ra[4 * ri + q][c];
#pragma unroll
            for (int v = 0; v < 8; ++v) {
                float4 m4 = *(const float4*)&Ma[ci + 16 * v][c];
#pragma unroll
                for (int q = 0; q < 4; ++q) {
                    acc[q][v] = fmaf(a4[q].x, m4.x, fmaf(a4[q].y, m4.y,
                                fmaf(a4[q].z, m4.z, fmaf(a4[q].w, m4.w, acc[q][v]))));
                }
            }
        }
#pragma unroll
        for (int v = 0; v < 8; ++v) {
            int ml = ci + 16 * v;
            float sqv = sqm[ml];
            int mg = m0 + ml;
#pragma unroll
            for (int q = 0; q < 4; ++q) {
                float cand = 2.0f * acc[q][v] - sqv;
                if (cand > tv[q][8]) {
                    tv[q][8] = cand; ti[q][8] = mg;
#pragma unroll
                    for (int t = 8; t > 0; --t) {
                        if (tv[q][t] > tv[q][t - 1]) {
                            float tmpv = tv[q][t]; tv[q][t] = tv[q][t - 1]; tv[q][t - 1] = tmpv;
                            int tmpi = ti[q][t]; ti[q][t] = ti[q][t - 1]; ti[q][t - 1] = tmpi;
                        }
                    }
                }
            }
        }
    }
    __syncthreads();
    float* mV = smem;
    int*   mI = (int*)(smem + 64 * 145);
#pragma unroll
    for (int q = 0; q < 4; ++q)
#pragma unroll
        for (int t = 0; t < 9; ++t) {
            mV[(4 * ri + q) * 145 + ci * 9 + t] = tv[q][t];
            mI[(4 * ri + q) * 145 + ci * 9 + t] = ti[q][t];
        }
    __syncthreads();
    if (threadIdx.x < 64) {
        int r = threadIdx.x;
        float* V = mV + r * 145;
        int*   I = mI + r * 145;
        size_t outbase = ((size_t)(b * 2048) + n0 + r) * 12;
        for (int pass = 0; pass < 12; ++pass) {
            float best = -3.4e38f; int bi = 1 << 30; int bp = 0;
            for (int j = 0; j < 144; ++j) {
                float v = V[j];
                int id = I[j];
                if (v > best || (v == best && id < bi)) { best = v; bi = id; bp = j; }
            }
            V[bp] = -3.4e38f;
            cand_out[outbase + pass] = bi;
        }
    }
}

// ---------------- knn stage 2 (f64): exact rescore of 12 candidates, pick top-9 (stable ties)
__global__ __launch_bounds__(256) void rescore_kernel(
    const double* __restrict__ xt64, const int* __restrict__ cand, int* __restrict__ idx_out)
{
    const int wid = threadIdx.x >> 6, lane = threadIdx.x & 63;
    const int n = blockIdx.x * 4 + wid;
    const int b = n >> 11;
    const double* Xb = xt64 + (size_t)b * 2048 * 128;
    const double* xr = xt64 + (size_t)n * 128;
    double a0 = xr[lane * 2], a1 = xr[lane * 2 + 1];
    double snn = a0 * a0 + a1 * a1;
#pragma unroll
    for (int off = 32; off > 0; off >>= 1) snn += __shfl_xor(snn, off);
    double invn = 1.0 / fmax(sqrt(snn), 1e-12);
    double sc[12]; int cd[12];
#pragma unroll
    for (int k = 0; k < 12; ++k) {
        int m = cand[(size_t)n * 12 + k];
        const double* xm = Xb + (size_t)m * 128;
        double m0v = xm[lane * 2], m1v = xm[lane * 2 + 1];
        double dnm = a0 * m0v + a1 * m1v;
        double dmm = m0v * m0v + m1v * m1v;
#pragma unroll
        for (int off = 32; off > 0; off >>= 1) {
            dnm += __shfl_xor(dnm, off);
            dmm += __shfl_xor(dmm, off);
        }
        double invm = 1.0 / fmax(sqrt(dmm), 1e-12);
        sc[k] = 2.0 * dnm * invn * invm - dmm * invm * invm;
        cd[k] = m;
    }
    if (lane == 0) {
        unsigned usedmask = 0;
        size_t ob = (size_t)n * 9;
        for (int p = 0; p < 9; ++p) {
            double best = -1.0e300; int bi = 1 << 30; int bp = 0;
#pragma unroll
            for (int j = 0; j < 12; ++j) {
                if (usedmask & (1u << j)) continue;
                if (sc[j] > best || (sc[j] == best && cd[j] < bi)) { best = sc[j]; bi = cd[j]; bp = j; }
            }
            usedmask |= 1u << bp;
            idx_out[ob + p] = bi;
        }
    }
}

// ---------------- f64 GEMM (K=128). mode 0: G=Xt@[W1;W2]^T (ld 256); 1: gelu affine; 2: affine (+f32 copy)
__global__ __launch_bounds__(256) void gemm64_kernel(
    const double* __restrict__ A, const float* __restrict__ W,
    const float* __restrict__ bias, const float* __restrict__ gamma,
    const float* __restrict__ beta, double* __restrict__ out,
    float* __restrict__ out32, int mode)
{
    __shared__ double As[64][130];
    __shared__ double Ws[64][130];
    const int m0 = blockIdx.x * 64;
    const int j0 = blockIdx.y * 64;
    for (int e = threadIdx.x; e < 64 * 128; e += 256) {
        int r = e >> 7, c = e & 127;
        As[r][c] = A[(size_t)(m0 + r) * 128 + c];
        int j = j0 + r;
        double wv;
        if (mode == 0) wv = (j < 128) ? (double)W[j * 256 + c] : (double)W[(j - 128) * 256 + 128 + c];
        else           wv = (double)W[j * 128 + c];
        Ws[r][c] = wv;
    }
    __syncthreads();
    const int ri = threadIdx.x >> 4, ci = threadIdx.x & 15;
    double acc[4][4];
#pragma unroll
    for (int u = 0; u < 4; ++u)
#pragma unroll
        for (int v = 0; v < 4; ++v) acc[u][v] = 0.0;
    for (int c = 0; c < 128; c += 2) {
        double a0[4], a1[4], w0[4], w1[4];
#pragma unroll
        for (int u = 0; u < 4; ++u) { a0[u] = As[ri + 16 * u][c]; a1[u] = As[ri + 16 * u][c + 1]; }
#pragma unroll
        for (int v = 0; v < 4; ++v) { w0[v] = Ws[ci + 16 * v][c]; w1[v] = Ws[ci + 16 * v][c + 1]; }
#pragma unroll
        for (int u = 0; u < 4; ++u)
#pragma unroll
            for (int v = 0; v < 4; ++v)
                acc[u][v] = fma(a1[u], w1[v], fma(a0[u], w0[v], acc[u][v]));
    }
#pragma unroll
    for (int u = 0; u < 4; ++u) {
        int row = m0 + ri + 16 * u;
#pragma unroll
        for (int v = 0; v < 4; ++v) {
            int jl = ci + 16 * v;
            double val = acc[u][v];
            if (mode == 0) {
                out[(size_t)row * 256 + j0 + jl] = val;
            } else {
                int jg = j0 + jl;
                double z = (val + (double)bias[jg]) * (double)gamma[jg] + (double)beta[jg];
                if (mode == 1) {
                    out[(size_t)row * 128 + jg] = gelu64(z);
                } else {
                    out[(size_t)row * 128 + jg] = z;
                    out32[(size_t)row * 128 + jg] = (float)z;
                }
            }
        }
    }
}

// ---------------- combine64 (in-place residual): xt += max_k gelu((G1+b-G2_i+G2_j)*gamma+beta)
__global__ __launch_bounds__(256) void combine64_kernel(
    double* __restrict__ xt, const double* __restrict__ G,
    const int* __restrict__ idx, const float* __restrict__ bias,
    const float* __restrict__ gamma, const float* __restrict__ beta)
{
    const int row = blockIdx.x * 2 + (threadIdx.x >> 7);
    const int o = threadIdx.x & 127;
    const int b = row >> 11;
    const double* Gb = G + (size_t)(b * 2048) * 256;
    const int* id9 = idx + (size_t)row * 9;
    double g1  = G[(size_t)row * 256 + o];
    double g2i = G[(size_t)row * 256 + 128 + o];
    double base = g1 + (double)bias[o] - g2i;
    double gm = (double)gamma[o], bt = (double)beta[o];
    double mx = -1.0e300;
#pragma unroll
    for (int k = 0; k < 9; ++k) {
        int j = id9[k];
        double h = base + Gb[(size_t)j * 256 + 128 + o];
        double z = h * gm + bt;
        mx = fmax(mx, gelu64(z));
    }
    xt[(size_t)row * 128 + o] += mx;
}

// ---------------- f32 GEMM (block-2 value path). Same modes as gemm64 (mode 2: plain affine)
__global__ __launch_bounds__(256) void gemm128_kernel(
    const float* __restrict__ A, const float* __restrict__ W,
    const float* __restrict__ bias, const float* __restrict__ gamma,
    const float* __restrict__ beta, float* __restrict__ out, int mode)
{
    __shared__ float Al[128][132];
    __shared__ float Wl[128][132];
    const int m0 = blockIdx.x * 128;
    const int j0 = blockIdx.y * 128;
    for (int e = threadIdx.x; e < 128 * 32; e += 256) {
        int r = e >> 5, q = e & 31;
        *(float4*)&Al[r][q * 4] = *(const float4*)(A + (size_t)(m0 + r) * 128 + q * 4);
    }
    for (int e = threadIdx.x; e < 128 * 32; e += 256) {
        int jj = e >> 5, q = e & 31;
        int c = q * 4;
        const float* src;
        if (mode == 0) {
            int j = j0 + jj;
            src = (j < 128) ? (W + j * 256 + c) : (W + (j - 128) * 256 + 128 + c);
        } else {
            src = W + jj * 128 + c;
        }
        *(float4*)&Wl[jj][c] = *(const float4*)src;
    }
    __syncthreads();
    const int ri = threadIdx.x >> 4, ci = threadIdx.x & 15;
    float acc[8][8];
#pragma unroll
    for (int u = 0; u < 8; ++u)
#pragma unroll
        for (int v = 0; v < 8; ++v) acc[u][v] = 0.0f;
    for (int c = 0; c < 128; c += 4) {
        float4 a4[8];
#pragma unroll
        for (int u = 0; u < 8; ++u) a4[u] = *(const float4*)&Al[ri + 16 * u][c];
#pragma unroll
        for (int v = 0; v < 8; ++v) {
            float4 w4 = *(const float4*)&Wl[ci + 16 * v][c];
#pragma unroll
            for (int u = 0; u < 8; ++u) {
                acc[u][v] = fmaf(a4[u].x, w4.x, fmaf(a4[u].y, w4.y,
                            fmaf(a4[u].z, w4.z, fmaf(a4[u].w, w4.w, acc[u][v]))));
            }
        }
    }
#pragma unroll
    for (int u = 0; u < 8; ++u) {
        int row = m0 + ri + 16 * u;
#pragma unroll
        for (int v = 0; v < 8; ++v) {
            int j = ci + 16 * v;
            float val = acc[u][v];
            if (mode == 0) {
                out[(size_t)row * 256 + j0 + j] = val;
            } else if (mode == 1) {
                float z = (val + bias[j]) * gamma[j] + beta[j];
                out[(size_t)row * 128 + j] = gelu_exact(z);
            } else {
                float z = (val + bias[j]) * gamma[j] + beta[j];
                out[(size_t)row * 128 + j] = z;
            }
        }
    }
}

// ---------------- combine f32 (block 2; in-place safe: reads only own row of xt)
__global__ __launch_bounds__(256) void combine_kernel(
    const float* __restrict__ xt, const float* __restrict__ G,
    const int* __restrict__ idx, const float* __restrict__ bias,
    const float* __restrict__ gamma, const float* __restrict__ beta,
    float* __restrict__ xt2)
{
    const int row = blockIdx.x * 2 + (threadIdx.x >> 7);
    const int o = threadIdx.x & 127;
    const int b = row >> 11;
    const float* Gb = G + (size_t)(b * 2048) * 256;
    const int* id9 = idx + (size_t)row * 9;
    float g1  = G[(size_t)row * 256 + o];
    float g2i = G[(size_t)row * 256 + 128 + o];
    float base = g1 + bias[o] - g2i;
    float gm = gamma[o], bt = beta[o];
    float mx = -3.4e38f;
#pragma unroll
    for (int k = 0; k < 9; ++k) {
        int j = id9[k];
        float h = base + Gb[(size_t)j * 256 + 128 + o];
        float z = h * gm + bt;
        mx = fmaxf(mx, gelu_exact(z));
    }
    xt2[(size_t)row * 128 + o] = xt[(size_t)row * 128 + o] + mx;
}

extern "C" void kernel_launch(void* const* d_in, const int* in_sizes, int n_in,
                              void* d_out, int out_size, void* d_ws, size_t ws_size,
                              hipStream_t stream)
{
    const float* ts       = (const float*)d_in[0];
    const float* conv1_w  = (const float*)d_in[1];
    const float* conv1_b  = (const float*)d_in[2];
    const float* conv2_w  = (const float*)d_in[3];
    const float* conv2_b  = (const float*)d_in[4];
    const float* gconv_w  = (const float*)d_in[5];
    const float* gconv_b  = (const float*)d_in[6];
    const float* gconv_g  = (const float*)d_in[7];
    const float* gconv_be = (const float*)d_in[8];
    const float* ffn1_w   = (const float*)d_in[9];
    const float* ffn1_b   = (const float*)d_in[10];
    const float* ffn1_g   = (const float*)d_in[11];
    const float* ffn1_be  = (const float*)d_in[12];
    const float* ffn2_w   = (const float*)d_in[13];
    const float* ffn2_b   = (const float*)d_in[14];
    const float* ffn2_g   = (const float*)d_in[15];
    const float* ffn2_be  = (const float*)d_in[16];
    (void)in_sizes; (void)n_in; (void)out_size; (void)ws_size;

    // ---- workspace layout (byte offsets), lifetime-overlaid; peak ~102 MB ----
    char* base = (char*)d_ws;
    double* XT64  = (double*)(base + 0);            // 33.55 MB; xt64; later in-place xt2_64 / xt64'
    double* H1_64 = (double*)(base + 33554432);     // 16.78 MB (conv phase only)
    float*  XN32  = (float*) (base + 33554432);     // 16.78 MB (norm -> stage1)
    int*    CAND  = (int*)   (base + 50331648);     // 1.57 MB  (stage1 -> rescore)
    float*  SQ32  = (float*) (base + 51904512);     // 0.13 MB
    double* G64   = (double*)(base + 33554432);     // 67.11 MB (gemm0 -> combine, blk1)
    double* H64   = (double*)(base + 33554432);     // 33.55 MB (ffn1 -> ffn2, blk1)
    float*  XT32P = (float*) (base + 67108864);     // 16.78 MB (blk1 ffn2 -> blk2 value path)
    int*    IDX   = (int*)   (base + 100663296);    // 1.18 MB  (rescore -> combine)
    float*  G32   = (float*) (base + 33554432);     // 33.55 MB (blk2)
    float*  H32   = (float*) (base + 33554432);     // 16.78 MB (blk2 ffn)

    float* fout = (float*)d_out;

    conv1_kernel64<<<dim3(64, 16), 256, 0, stream>>>(ts, conv1_w, conv1_b, H1_64);
    conv2_kernel64<<<dim3(64, 16), 256, 0, stream>>>(H1_64, conv2_w, conv2_b, XT64);

    // ---------- block 1 (f64 value path; indices exact) ----------
    norm32_kernel<<<8192, 256, 0, stream>>>(XT64, XN32, SQ32);
    knn_kernel<<<dim3(32, 16), 256, 0, stream>>>(XN32, SQ32, CAND);
    rescore_kernel<<<8192, 256, 0, stream>>>(XT64, CAND, IDX);
    gemm64_kernel<<<dim3(512, 4), 256, 0, stream>>>(
        XT64, gconv_w, nullptr, nullptr, nullptr, G64, nullptr, 0);
    combine64_kernel<<<16384, 256, 0, stream>>>(
        XT64, G64, IDX, gconv_b, gconv_g, gconv_be);
    gemm64_kernel<<<dim3(512, 2), 256, 0, stream>>>(
        XT64, ffn1_w, ffn1_b, ffn1_g, ffn1_be, H64, nullptr, 1);
    gemm64_kernel<<<dim3(512, 2), 256, 0, stream>>>(
        H64, ffn2_w, ffn2_b, ffn2_g, ffn2_be, XT64, XT32P, 2);

    // ---------- block 2 (indices exact via f64; value path f32) ----------
    norm32_kernel<<<8192, 256, 0, stream>>>(XT64, XN32, SQ32);
    knn_kernel<<<dim3(32, 16), 256, 0, stream>>>(XN32, SQ32, CAND);
    rescore_kernel<<<8192, 256, 0, stream>>>(XT64, CAND, IDX);
    gemm128_kernel<<<dim3(256, 2), 256, 0, stream>>>(
        XT32P, gconv_w + 32768, nullptr, nullptr, nullptr, G32, 0);
    combine_kernel<<<16384, 256, 0, stream>>>(
        XT32P, G32, IDX, gconv_b + 128, gconv_g + 128, gconv_be + 128, XT32P);
    gemm128_kernel<<<dim3(256, 1), 256, 0, stream>>>(
        XT32P, ffn1_w + 16384, ffn1_b + 128, ffn1_g + 128, ffn1_be + 128, H32, 1);
    gemm128_kernel<<<dim3(256, 1), 256, 0, stream>>>(
        H32, ffn2_w + 16384, ffn2_b + 128, ffn2_g + 128, ffn2_be + 128, fout, 2);
}